// Round 1
// baseline (1008.089 us; speedup 1.0000x reference)
//
#include <hip/hip_runtime.h>
#include <math.h>

// GraphSAGE, 2 layers, N=100000, E=1.6M, D=128.
// Strategy: build CSR-by-dst each call (count -> scan -> place), then one
// fused kernel per layer: per 32-row tile, aggregate incoming edges into LDS,
// then compute out = agg@Wn + x@Ws + bias with activation, write to next buf.

#define D 128

__global__ void k_count(const int* __restrict__ dst, int E, int* __restrict__ cnt) {
    int e = blockIdx.x * 256 + threadIdx.x;
    if (e < E) atomicAdd(&cnt[dst[e]], 1);
}

// block=256 threads, chunk=512 elements: partial[b] = sum of cnt in chunk b
__global__ void k_scanA(const int* __restrict__ cnt, int N, int* __restrict__ partial) {
    __shared__ int s[256];
    int t = threadIdx.x;
    int base = blockIdx.x * 512;
    int v = 0;
    if (base + t < N) v += cnt[base + t];
    if (base + 256 + t < N) v += cnt[base + 256 + t];
    s[t] = v;
    __syncthreads();
    for (int off = 128; off > 0; off >>= 1) {
        if (t < off) s[t] += s[t + off];
        __syncthreads();
    }
    if (t == 0) partial[blockIdx.x] = s[0];
}

// single thread: exclusive scan of NB partials (NB ~196, trivial)
__global__ void k_scanB(const int* __restrict__ partial, int NB, int* __restrict__ blockoff) {
    if (threadIdx.x == 0 && blockIdx.x == 0) {
        int acc = 0;
        for (int b = 0; b < NB; ++b) { blockoff[b] = acc; acc += partial[b]; }
    }
}

// block=512 threads, one element each: within-chunk exclusive scan + chunk offset
__global__ void k_scanC(const int* __restrict__ cnt, int N, const int* __restrict__ blockoff,
                        int* __restrict__ row_start, int* __restrict__ cursor) {
    __shared__ int s[512];
    int t = threadIdx.x;
    int i = blockIdx.x * 512 + t;
    int v = (i < N) ? cnt[i] : 0;
    s[t] = v;
    __syncthreads();
    for (int off = 1; off < 512; off <<= 1) {
        int u = (t >= off) ? s[t - off] : 0;
        __syncthreads();
        s[t] += u;
        __syncthreads();
    }
    if (i < N) {
        int excl = blockoff[blockIdx.x] + s[t] - v;
        row_start[i] = excl;
        cursor[i] = excl;
    }
}

__global__ void k_place(const int* __restrict__ src, const int* __restrict__ dst,
                        const float* __restrict__ w, int E,
                        int* __restrict__ cursor,
                        int* __restrict__ srcs, float* __restrict__ wsort) {
    int e = blockIdx.x * 256 + threadIdx.x;
    if (e < E) {
        int d = dst[e];
        int p = atomicAdd(&cursor[d], 1);
        srcs[p] = src[e];
        wsort[p] = w[e];
    }
}

// Fused layer: 32 rows per block. Phase 1: each wave aggregates rows (mean of
// weighted neighbor rows) into sA and stages own row into sX. Phase 2: tile
// GEMM out = sA@Wn + sX@Ws + bias, activation, store.
// ACT: 0 = relu, 1 = sigmoid
template <int ACT>
__global__ __launch_bounds__(256, 4) void k_layer(
    const float* __restrict__ xin, float* __restrict__ xout,
    const int* __restrict__ srcs, const float* __restrict__ wsort,
    const int* __restrict__ row_start, const int* __restrict__ cnt,
    const float* __restrict__ Wn, const float* __restrict__ Ws,
    const float* __restrict__ bias, int N)
{
    __shared__ float sA[32][D];
    __shared__ float sX[32][D];
    const int tid = threadIdx.x;
    const int lane = tid & 63;
    const int wv = tid >> 6;          // 4 waves
    const int brow = blockIdx.x * 32;

    // ---- phase 1: aggregation (one wave per row, float2 per lane) ----
    for (int r = wv; r < 32; r += 4) {
        int node = brow + r;
        if (node < N) {
            int st = row_start[node];
            int num = cnt[node];
            float ax = 0.f, ay = 0.f;
            for (int e = st; e < st + num; ++e) {
                int s = srcs[e];
                float wt = wsort[e];
                const float2 v = *reinterpret_cast<const float2*>(&xin[(size_t)s * D + lane * 2]);
                ax += wt * v.x;
                ay += wt * v.y;
            }
            float invd = 1.0f / (float)(num > 1 ? num : 1);
            sA[r][lane * 2]     = ax * invd;
            sA[r][lane * 2 + 1] = ay * invd;
            const float2 xv = *reinterpret_cast<const float2*>(&xin[(size_t)node * D + lane * 2]);
            sX[r][lane * 2]     = xv.x;
            sX[r][lane * 2 + 1] = xv.y;
        }
    }
    __syncthreads();

    // ---- phase 2: GEMM. 256 threads = 32 tx (col groups of 4) x 8 ty (row groups of 4)
    const int tx = tid & 31;
    const int ty = tid >> 5;
    const int j0 = tx * 4;
    const int i0 = ty * 4;

    float acc[4][4];
#pragma unroll
    for (int i = 0; i < 4; ++i)
#pragma unroll
        for (int j = 0; j < 4; ++j) acc[i][j] = 0.f;

    for (int k = 0; k < D; k += 4) {
        float4 a4[4], x4[4];
#pragma unroll
        for (int i = 0; i < 4; ++i) {
            a4[i] = *reinterpret_cast<const float4*>(&sA[i0 + i][k]);
            x4[i] = *reinterpret_cast<const float4*>(&sX[i0 + i][k]);
        }
#pragma unroll
        for (int kk = 0; kk < 4; ++kk) {
            const float4 wn = *reinterpret_cast<const float4*>(&Wn[(size_t)(k + kk) * D + j0]);
            const float4 ws = *reinterpret_cast<const float4*>(&Ws[(size_t)(k + kk) * D + j0]);
#pragma unroll
            for (int i = 0; i < 4; ++i) {
                float a  = reinterpret_cast<const float*>(&a4[i])[kk];
                float xx = reinterpret_cast<const float*>(&x4[i])[kk];
                acc[i][0] += a * wn.x + xx * ws.x;
                acc[i][1] += a * wn.y + xx * ws.y;
                acc[i][2] += a * wn.z + xx * ws.z;
                acc[i][3] += a * wn.w + xx * ws.w;
            }
        }
    }

    const float4 bv = *reinterpret_cast<const float4*>(&bias[j0]);
#pragma unroll
    for (int i = 0; i < 4; ++i) {
        int row = brow + i0 + i;
        if (row < N) {
            float4 o;
            o.x = acc[i][0] + bv.x;
            o.y = acc[i][1] + bv.y;
            o.z = acc[i][2] + bv.z;
            o.w = acc[i][3] + bv.w;
            if (ACT == 0) {
                o.x = fmaxf(o.x, 0.f);
                o.y = fmaxf(o.y, 0.f);
                o.z = fmaxf(o.z, 0.f);
                o.w = fmaxf(o.w, 0.f);
            } else {
                o.x = 1.f / (1.f + __expf(-o.x));
                o.y = 1.f / (1.f + __expf(-o.y));
                o.z = 1.f / (1.f + __expf(-o.z));
                o.w = 1.f / (1.f + __expf(-o.w));
            }
            *reinterpret_cast<float4*>(&xout[(size_t)row * D + j0]) = o;
        }
    }
}

extern "C" void kernel_launch(void* const* d_in, const int* in_sizes, int n_in,
                              void* d_out, int out_size, void* d_ws, size_t ws_size,
                              hipStream_t stream) {
    const float* x      = (const float*)d_in[0];
    const int*   ei     = (const int*)d_in[1];
    const float* ew     = (const float*)d_in[2];
    const float* W_self = (const float*)d_in[3];
    const float* W_neigh= (const float*)d_in[4];
    const float* bias   = (const float*)d_in[5];
    float* out = (float*)d_out;

    const int N = in_sizes[0] / D;
    const int E = in_sizes[2];
    const int L = in_sizes[5] / D;   // bias is [L, D]

    const int* src = ei;        // edge_index[0]
    const int* dst = ei + E;    // edge_index[1]

    // carve workspace (256B aligned)
    char* p = (char*)d_ws;
    auto carve = [&](size_t bytes) -> void* {
        void* r = (void*)p;
        p += (bytes + 255) & ~(size_t)255;
        return r;
    };
    const int NB = (N + 511) / 512;
    int*   cnt       = (int*)carve((size_t)N * 4);
    int*   row_start = (int*)carve((size_t)N * 4);
    int*   cursor    = (int*)carve((size_t)N * 4);
    int*   partial   = (int*)carve((size_t)NB * 4);
    int*   blockoff  = (int*)carve((size_t)NB * 4);
    int*   srcs      = (int*)carve((size_t)E * 4);
    float* wsort     = (float*)carve((size_t)E * 4);
    float* buf0      = (float*)carve((size_t)N * D * 4);
    float* buf1      = (float*)carve((size_t)N * D * 4);  // only touched if L > 2

    // ---- CSR build ----
    hipMemsetAsync(cnt, 0, (size_t)N * 4, stream);
    k_count<<<(E + 255) / 256, 256, 0, stream>>>(dst, E, cnt);
    k_scanA<<<NB, 256, 0, stream>>>(cnt, N, partial);
    k_scanB<<<1, 64, 0, stream>>>(partial, NB, blockoff);
    k_scanC<<<NB, 512, 0, stream>>>(cnt, N, blockoff, row_start, cursor);
    k_place<<<(E + 255) / 256, 256, 0, stream>>>(src, dst, ew, E, cursor, srcs, wsort);

    // ---- layers ----
    const int nblk = (N + 31) / 32;
    const float* cur = x;
    for (int l = 0; l < L; ++l) {
        const float* Wn = W_neigh + (size_t)l * D * D;
        const float* Ws = W_self  + (size_t)l * D * D;
        const float* bl = bias + (size_t)l * D;
        float* nxt;
        if (l == L - 1) nxt = out;
        else            nxt = (l & 1) ? buf1 : buf0;
        if (l < L - 1) {
            k_layer<0><<<nblk, 256, 0, stream>>>(cur, nxt, srcs, wsort, row_start, cnt,
                                                 Wn, Ws, bl, N);
        } else {
            k_layer<1><<<nblk, 256, 0, stream>>>(cur, nxt, srcs, wsort, row_start, cnt,
                                                 Wn, Ws, bl, N);
        }
        cur = nxt;
    }
}

// Round 2
// 667.447 us; speedup vs baseline: 1.5104x; 1.5104x over previous
//
#include <hip/hip_runtime.h>
#include <math.h>

// GraphSAGE, 2 layers, N=100000, E=1.6M, D=128.
// CSR build (count -> scan -> place), then per layer:
//   k_agg : one wave per node, 4 edge-slots x 16 col-groups, float4 gathers
//   k_gemm: out = agg@Wn + x@Ws + bias, activation (fp32 register-tiled)

#define D 128

__global__ void k_count(const int* __restrict__ dst, int E, int* __restrict__ cnt) {
    int e = blockIdx.x * 256 + threadIdx.x;
    if (e < E) atomicAdd(&cnt[dst[e]], 1);
}

// block=256 threads, chunk=512 elements: partial[b] = sum of cnt in chunk b
__global__ void k_scanA(const int* __restrict__ cnt, int N, int* __restrict__ partial) {
    __shared__ int s[256];
    int t = threadIdx.x;
    int base = blockIdx.x * 512;
    int v = 0;
    if (base + t < N) v += cnt[base + t];
    if (base + 256 + t < N) v += cnt[base + 256 + t];
    s[t] = v;
    __syncthreads();
    for (int off = 128; off > 0; off >>= 1) {
        if (t < off) s[t] += s[t + off];
        __syncthreads();
    }
    if (t == 0) partial[blockIdx.x] = s[0];
}

__global__ void k_scanB(const int* __restrict__ partial, int NB, int* __restrict__ blockoff) {
    if (threadIdx.x == 0 && blockIdx.x == 0) {
        int acc = 0;
        for (int b = 0; b < NB; ++b) { blockoff[b] = acc; acc += partial[b]; }
    }
}

__global__ void k_scanC(const int* __restrict__ cnt, int N, const int* __restrict__ blockoff,
                        int* __restrict__ row_start, int* __restrict__ cursor) {
    __shared__ int s[512];
    int t = threadIdx.x;
    int i = blockIdx.x * 512 + t;
    int v = (i < N) ? cnt[i] : 0;
    s[t] = v;
    __syncthreads();
    for (int off = 1; off < 512; off <<= 1) {
        int u = (t >= off) ? s[t - off] : 0;
        __syncthreads();
        s[t] += u;
        __syncthreads();
    }
    if (i < N) {
        int excl = blockoff[blockIdx.x] + s[t] - v;
        row_start[i] = excl;
        cursor[i] = excl;
    }
}

__global__ void k_place(const int* __restrict__ src, const int* __restrict__ dst,
                        const float* __restrict__ w, int E,
                        int* __restrict__ cursor,
                        int* __restrict__ srcs, float* __restrict__ wsort) {
    int e = blockIdx.x * 256 + threadIdx.x;
    if (e < E) {
        int d = dst[e];
        int p = atomicAdd(&cursor[d], 1);
        srcs[p] = src[e];
        wsort[p] = w[e];
    }
}

// One wave per node. Lane = q*16 + c16: q = edge slot (4 concurrent edges),
// c16 = float4 column group. Each lane gathers 2 float4 (cols c16, c16+16).
__global__ __launch_bounds__(256, 8) void k_agg(
    const float* __restrict__ xin,
    const int* __restrict__ srcs, const float* __restrict__ wsort,
    const int* __restrict__ row_start, const int* __restrict__ cnt,
    float* __restrict__ agg, int N)
{
    const int tid = threadIdx.x;
    const int wv = tid >> 6;
    const int lane = tid & 63;
    const int node = blockIdx.x * 4 + wv;
    if (node >= N) return;
    const int q = lane >> 4;
    const int c16 = lane & 15;
    const int st = row_start[node];
    const int num = cnt[node];
    const int en = st + num;

    float a0x = 0.f, a0y = 0.f, a0z = 0.f, a0w = 0.f;
    float a1x = 0.f, a1y = 0.f, a1z = 0.f, a1w = 0.f;

#pragma unroll 2
    for (int e = st + q; e < en; e += 4) {
        const int s = srcs[e];
        const float w = wsort[e];
        const float4* xr = reinterpret_cast<const float4*>(xin + (size_t)s * D);
        const float4 v0 = xr[c16];
        const float4 v1 = xr[c16 + 16];
        a0x = fmaf(w, v0.x, a0x); a0y = fmaf(w, v0.y, a0y);
        a0z = fmaf(w, v0.z, a0z); a0w = fmaf(w, v0.w, a0w);
        a1x = fmaf(w, v1.x, a1x); a1y = fmaf(w, v1.y, a1y);
        a1z = fmaf(w, v1.z, a1z); a1w = fmaf(w, v1.w, a1w);
    }

    // reduce across the 4 edge slots (lanes q*16+c16): xor 16 then xor 32
#define RED1(c) c += __shfl_xor(c, 16); c += __shfl_xor(c, 32);
    RED1(a0x) RED1(a0y) RED1(a0z) RED1(a0w)
    RED1(a1x) RED1(a1y) RED1(a1z) RED1(a1w)
#undef RED1

    if (q == 0) {
        const float invd = 1.0f / (float)(num > 1 ? num : 1);
        float4 o0, o1;
        o0.x = a0x * invd; o0.y = a0y * invd; o0.z = a0z * invd; o0.w = a0w * invd;
        o1.x = a1x * invd; o1.y = a1y * invd; o1.z = a1z * invd; o1.w = a1w * invd;
        float4* ar = reinterpret_cast<float4*>(agg + (size_t)node * D);
        ar[c16] = o0;
        ar[c16 + 16] = o1;
    }
}

// 32 rows per block: stage agg+x rows in LDS, register-tiled fp32 GEMM.
// ACT: 0 = relu, 1 = sigmoid
template <int ACT>
__global__ __launch_bounds__(256, 4) void k_gemm(
    const float* __restrict__ agg, const float* __restrict__ xin,
    const float* __restrict__ Wn, const float* __restrict__ Ws,
    const float* __restrict__ bias, float* __restrict__ xout, int N)
{
    __shared__ float sA[32][D];
    __shared__ float sX[32][D];
    const int tid = threadIdx.x;
    const int brow = blockIdx.x * 32;

    // stage 32 rows of agg and x (1024 float4 each)
    for (int i = tid; i < 1024; i += 256) {
        int r = i >> 5;
        int c = (i & 31) * 4;
        int row = brow + r;
        float4 va = {0.f, 0.f, 0.f, 0.f}, vx = {0.f, 0.f, 0.f, 0.f};
        if (row < N) {
            va = *reinterpret_cast<const float4*>(agg + (size_t)row * D + c);
            vx = *reinterpret_cast<const float4*>(xin + (size_t)row * D + c);
        }
        *reinterpret_cast<float4*>(&sA[r][c]) = va;
        *reinterpret_cast<float4*>(&sX[r][c]) = vx;
    }
    __syncthreads();

    const int tx = tid & 31;
    const int ty = tid >> 5;
    const int j0 = tx * 4;
    const int i0 = ty * 4;

    float acc[4][4];
#pragma unroll
    for (int i = 0; i < 4; ++i)
#pragma unroll
        for (int j = 0; j < 4; ++j) acc[i][j] = 0.f;

    for (int k = 0; k < D; k += 4) {
        float4 a4[4], x4[4];
#pragma unroll
        for (int i = 0; i < 4; ++i) {
            a4[i] = *reinterpret_cast<const float4*>(&sA[i0 + i][k]);
            x4[i] = *reinterpret_cast<const float4*>(&sX[i0 + i][k]);
        }
#pragma unroll
        for (int kk = 0; kk < 4; ++kk) {
            const float4 wn = *reinterpret_cast<const float4*>(&Wn[(size_t)(k + kk) * D + j0]);
            const float4 ws = *reinterpret_cast<const float4*>(&Ws[(size_t)(k + kk) * D + j0]);
#pragma unroll
            for (int i = 0; i < 4; ++i) {
                float a  = reinterpret_cast<const float*>(&a4[i])[kk];
                float xx = reinterpret_cast<const float*>(&x4[i])[kk];
                acc[i][0] = fmaf(a, wn.x, fmaf(xx, ws.x, acc[i][0]));
                acc[i][1] = fmaf(a, wn.y, fmaf(xx, ws.y, acc[i][1]));
                acc[i][2] = fmaf(a, wn.z, fmaf(xx, ws.z, acc[i][2]));
                acc[i][3] = fmaf(a, wn.w, fmaf(xx, ws.w, acc[i][3]));
            }
        }
    }

    const float4 bv = *reinterpret_cast<const float4*>(&bias[j0]);
#pragma unroll
    for (int i = 0; i < 4; ++i) {
        int row = brow + i0 + i;
        if (row < N) {
            float4 o;
            o.x = acc[i][0] + bv.x;
            o.y = acc[i][1] + bv.y;
            o.z = acc[i][2] + bv.z;
            o.w = acc[i][3] + bv.w;
            if (ACT == 0) {
                o.x = fmaxf(o.x, 0.f);
                o.y = fmaxf(o.y, 0.f);
                o.z = fmaxf(o.z, 0.f);
                o.w = fmaxf(o.w, 0.f);
            } else {
                o.x = 1.f / (1.f + __expf(-o.x));
                o.y = 1.f / (1.f + __expf(-o.y));
                o.z = 1.f / (1.f + __expf(-o.z));
                o.w = 1.f / (1.f + __expf(-o.w));
            }
            *reinterpret_cast<float4*>(&xout[(size_t)row * D + j0]) = o;
        }
    }
}

extern "C" void kernel_launch(void* const* d_in, const int* in_sizes, int n_in,
                              void* d_out, int out_size, void* d_ws, size_t ws_size,
                              hipStream_t stream) {
    const float* x      = (const float*)d_in[0];
    const int*   ei     = (const int*)d_in[1];
    const float* ew     = (const float*)d_in[2];
    const float* W_self = (const float*)d_in[3];
    const float* W_neigh= (const float*)d_in[4];
    const float* bias   = (const float*)d_in[5];
    float* out = (float*)d_out;

    const int N = in_sizes[0] / D;
    const int E = in_sizes[2];
    const int L = in_sizes[5] / D;

    const int* src = ei;
    const int* dst = ei + E;

    char* p = (char*)d_ws;
    auto carve = [&](size_t bytes) -> void* {
        void* r = (void*)p;
        p += (bytes + 255) & ~(size_t)255;
        return r;
    };
    const int NB = (N + 511) / 512;
    int*   cnt       = (int*)carve((size_t)N * 4);
    int*   row_start = (int*)carve((size_t)N * 4);
    int*   cursor    = (int*)carve((size_t)N * 4);
    int*   partial   = (int*)carve((size_t)NB * 4);
    int*   blockoff  = (int*)carve((size_t)NB * 4);
    int*   srcs      = (int*)carve((size_t)E * 4);
    float* wsort     = (float*)carve((size_t)E * 4);
    float* aggbuf    = (float*)carve((size_t)N * D * 4);
    float* buf0      = (float*)carve((size_t)N * D * 4);
    float* buf1      = (float*)carve((size_t)N * D * 4);

    // ---- CSR build ----
    hipMemsetAsync(cnt, 0, (size_t)N * 4, stream);
    k_count<<<(E + 255) / 256, 256, 0, stream>>>(dst, E, cnt);
    k_scanA<<<NB, 256, 0, stream>>>(cnt, N, partial);
    k_scanB<<<1, 64, 0, stream>>>(partial, NB, blockoff);
    k_scanC<<<NB, 512, 0, stream>>>(cnt, N, blockoff, row_start, cursor);
    k_place<<<(E + 255) / 256, 256, 0, stream>>>(src, dst, ew, E, cursor, srcs, wsort);

    // ---- layers ----
    const int nblk_agg  = (N + 3) / 4;
    const int nblk_gemm = (N + 31) / 32;
    const float* cur = x;
    for (int l = 0; l < L; ++l) {
        const float* Wn = W_neigh + (size_t)l * D * D;
        const float* Ws = W_self  + (size_t)l * D * D;
        const float* bl = bias + (size_t)l * D;
        float* nxt;
        if (l == L - 1) nxt = out;
        else            nxt = (l & 1) ? buf1 : buf0;

        k_agg<<<nblk_agg, 256, 0, stream>>>(cur, srcs, wsort, row_start, cnt, aggbuf, N);
        if (l < L - 1) {
            k_gemm<0><<<nblk_gemm, 256, 0, stream>>>(aggbuf, cur, Wn, Ws, bl, nxt, N);
        } else {
            k_gemm<1><<<nblk_gemm, 256, 0, stream>>>(aggbuf, cur, Wn, Ws, bl, nxt, N);
        }
        cur = nxt;
    }
}

// Round 3
// 566.897 us; speedup vs baseline: 1.7783x; 1.1774x over previous
//
#include <hip/hip_runtime.h>
#include <math.h>

// GraphSAGE, 2 layers, N=100000, E=1.6M, D=128.
// CSR build (count -> scan -> packed place), x converted to bf16 once.
// Per layer: k_agg (wave/node, bf16 gathers, fp32 accum) -> k_gemm
// (fp32 register-tiled, bf16 intermediate write / fp32 final write).

#define D 128

typedef unsigned int uint;

__device__ __forceinline__ float bf_lo(uint u) { return __uint_as_float(u << 16); }
__device__ __forceinline__ float bf_hi(uint u) { return __uint_as_float(u & 0xffff0000u); }
__device__ __forceinline__ unsigned short f2bf(float f) {
    uint u = __float_as_uint(f);
    u += 0x7fffu + ((u >> 16) & 1u);   // round-to-nearest-even
    return (unsigned short)(u >> 16);
}
__device__ __forceinline__ uint pack2bf(float lo, float hi) {
    return (uint)f2bf(lo) | ((uint)f2bf(hi) << 16);
}

// ---- fp32 -> bf16 conversion of x (N*D elems, 8 per thread) ----
__global__ void k_convert(const float* __restrict__ in, uint* __restrict__ outb, int n8) {
    int i = blockIdx.x * 256 + threadIdx.x;
    if (i >= n8) return;
    const float4* p = reinterpret_cast<const float4*>(in + (size_t)i * 8);
    float4 a = p[0], b = p[1];
    uint4 o;
    o.x = pack2bf(a.x, a.y);
    o.y = pack2bf(a.z, a.w);
    o.z = pack2bf(b.x, b.y);
    o.w = pack2bf(b.z, b.w);
    reinterpret_cast<uint4*>(outb)[i] = o;
}

__global__ void k_count(const int* __restrict__ dst, int E, int* __restrict__ cnt) {
    int e = blockIdx.x * 256 + threadIdx.x;
    if (e < E) atomicAdd(&cnt[dst[e]], 1);
}

__global__ void k_scanA(const int* __restrict__ cnt, int N, int* __restrict__ partial) {
    __shared__ int s[256];
    int t = threadIdx.x;
    int base = blockIdx.x * 512;
    int v = 0;
    if (base + t < N) v += cnt[base + t];
    if (base + 256 + t < N) v += cnt[base + 256 + t];
    s[t] = v;
    __syncthreads();
    for (int off = 128; off > 0; off >>= 1) {
        if (t < off) s[t] += s[t + off];
        __syncthreads();
    }
    if (t == 0) partial[blockIdx.x] = s[0];
}

__global__ void k_scanB(const int* __restrict__ partial, int NB, int* __restrict__ blockoff) {
    if (threadIdx.x == 0 && blockIdx.x == 0) {
        int acc = 0;
        for (int b = 0; b < NB; ++b) { blockoff[b] = acc; acc += partial[b]; }
    }
}

__global__ void k_scanC(const int* __restrict__ cnt, int N, const int* __restrict__ blockoff,
                        int* __restrict__ row_start, int* __restrict__ cursor) {
    __shared__ int s[512];
    int t = threadIdx.x;
    int i = blockIdx.x * 512 + t;
    int v = (i < N) ? cnt[i] : 0;
    s[t] = v;
    __syncthreads();
    for (int off = 1; off < 512; off <<= 1) {
        int u = (t >= off) ? s[t - off] : 0;
        __syncthreads();
        s[t] += u;
        __syncthreads();
    }
    if (i < N) {
        int excl = blockoff[blockIdx.x] + s[t] - v;
        row_start[i] = excl;
        cursor[i] = excl;
    }
}

// packed scatter: one 8B write per edge (src, weight)
__global__ void k_place(const int* __restrict__ src, const int* __restrict__ dst,
                        const float* __restrict__ w, int E,
                        int* __restrict__ cursor, int2* __restrict__ srcw) {
    int e = blockIdx.x * 256 + threadIdx.x;
    if (e < E) {
        int d = dst[e];
        int p = atomicAdd(&cursor[d], 1);
        srcw[p] = make_int2(src[e], __float_as_int(w[e]));
    }
}

// One wave per node. lane = q*16 + c16: q = edge slot (4 concurrent edges),
// c16 = 8-col group. Each lane gathers one uint4 (8 bf16) per edge.
__global__ __launch_bounds__(256, 8) void k_agg(
    const uint* __restrict__ xb,          // bf16 features, packed 2/uint
    const int2* __restrict__ srcw,
    const int* __restrict__ row_start, const int* __restrict__ cnt,
    float* __restrict__ agg, int N)
{
    const int tid = threadIdx.x;
    const int wv = tid >> 6;
    const int lane = tid & 63;
    const int node = blockIdx.x * 4 + wv;
    if (node >= N) return;
    const int q = lane >> 4;
    const int c16 = lane & 15;
    const int st = row_start[node];
    const int num = cnt[node];
    const int en = st + num;

    float a[8];
#pragma unroll
    for (int j = 0; j < 8; ++j) a[j] = 0.f;

#pragma unroll 2
    for (int e = st + q; e < en; e += 4) {
        const int2 sw = srcw[e];
        const int s = sw.x;
        const float w = __int_as_float(sw.y);
        const uint4 v = reinterpret_cast<const uint4*>(xb + (size_t)s * (D / 2))[c16];
        a[0] = fmaf(w, bf_lo(v.x), a[0]);
        a[1] = fmaf(w, bf_hi(v.x), a[1]);
        a[2] = fmaf(w, bf_lo(v.y), a[2]);
        a[3] = fmaf(w, bf_hi(v.y), a[3]);
        a[4] = fmaf(w, bf_lo(v.z), a[4]);
        a[5] = fmaf(w, bf_hi(v.z), a[5]);
        a[6] = fmaf(w, bf_lo(v.w), a[6]);
        a[7] = fmaf(w, bf_hi(v.w), a[7]);
    }

#pragma unroll
    for (int j = 0; j < 8; ++j) {
        a[j] += __shfl_xor(a[j], 16);
        a[j] += __shfl_xor(a[j], 32);
    }

    if (q == 0) {
        const float invd = 1.0f / (float)(num > 1 ? num : 1);
        float4 o0, o1;
        o0.x = a[0] * invd; o0.y = a[1] * invd; o0.z = a[2] * invd; o0.w = a[3] * invd;
        o1.x = a[4] * invd; o1.y = a[5] * invd; o1.z = a[6] * invd; o1.w = a[7] * invd;
        float4* ar = reinterpret_cast<float4*>(agg + (size_t)node * D + c16 * 8);
        ar[0] = o0;
        ar[1] = o1;
    }
}

// 32 rows/block: stage agg (fp32) + x (bf16->fp32) in LDS, register-tiled GEMM.
// ACT: 0 = relu, 1 = sigmoid. OUTB: 1 = write bf16 (packed), 0 = write fp32.
template <int ACT, int OUTB>
__global__ __launch_bounds__(256, 4) void k_gemm(
    const float* __restrict__ agg, const uint* __restrict__ xb,
    const float* __restrict__ Wn, const float* __restrict__ Ws,
    const float* __restrict__ bias, void* __restrict__ xout, int N)
{
    __shared__ float sA[32][D];
    __shared__ float sX[32][D];
    const int tid = threadIdx.x;
    const int brow = blockIdx.x * 32;

    // stage agg rows (fp32, 1024 float4)
    for (int i = tid; i < 1024; i += 256) {
        int r = i >> 5;
        int c = (i & 31) * 4;
        int row = brow + r;
        float4 va = {0.f, 0.f, 0.f, 0.f};
        if (row < N) va = *reinterpret_cast<const float4*>(agg + (size_t)row * D + c);
        *reinterpret_cast<float4*>(&sA[r][c]) = va;
    }
    // stage x rows (bf16 -> fp32, 512 uint4)
    for (int i = tid; i < 512; i += 256) {
        int r = i >> 4;
        int c8 = (i & 15) * 8;
        int row = brow + r;
        uint4 v = {0, 0, 0, 0};
        if (row < N) v = reinterpret_cast<const uint4*>(xb + (size_t)row * (D / 2))[i & 15];
        float* dstp = &sX[r][c8];
        dstp[0] = bf_lo(v.x); dstp[1] = bf_hi(v.x);
        dstp[2] = bf_lo(v.y); dstp[3] = bf_hi(v.y);
        dstp[4] = bf_lo(v.z); dstp[5] = bf_hi(v.z);
        dstp[6] = bf_lo(v.w); dstp[7] = bf_hi(v.w);
    }
    __syncthreads();

    const int tx = tid & 31;
    const int ty = tid >> 5;
    const int j0 = tx * 4;
    const int i0 = ty * 4;

    float acc[4][4];
#pragma unroll
    for (int i = 0; i < 4; ++i)
#pragma unroll
        for (int j = 0; j < 4; ++j) acc[i][j] = 0.f;

    for (int k = 0; k < D; k += 4) {
        float4 a4[4], x4[4];
#pragma unroll
        for (int i = 0; i < 4; ++i) {
            a4[i] = *reinterpret_cast<const float4*>(&sA[i0 + i][k]);
            x4[i] = *reinterpret_cast<const float4*>(&sX[i0 + i][k]);
        }
#pragma unroll
        for (int kk = 0; kk < 4; ++kk) {
            const float4 wn = *reinterpret_cast<const float4*>(&Wn[(size_t)(k + kk) * D + j0]);
            const float4 ws = *reinterpret_cast<const float4*>(&Ws[(size_t)(k + kk) * D + j0]);
#pragma unroll
            for (int i = 0; i < 4; ++i) {
                float a  = reinterpret_cast<const float*>(&a4[i])[kk];
                float xx = reinterpret_cast<const float*>(&x4[i])[kk];
                acc[i][0] = fmaf(a, wn.x, fmaf(xx, ws.x, acc[i][0]));
                acc[i][1] = fmaf(a, wn.y, fmaf(xx, ws.y, acc[i][1]));
                acc[i][2] = fmaf(a, wn.z, fmaf(xx, ws.z, acc[i][2]));
                acc[i][3] = fmaf(a, wn.w, fmaf(xx, ws.w, acc[i][3]));
            }
        }
    }

    const float4 bv = *reinterpret_cast<const float4*>(&bias[j0]);
#pragma unroll
    for (int i = 0; i < 4; ++i) {
        int row = brow + i0 + i;
        if (row < N) {
            float4 o;
            o.x = acc[i][0] + bv.x;
            o.y = acc[i][1] + bv.y;
            o.z = acc[i][2] + bv.z;
            o.w = acc[i][3] + bv.w;
            if (ACT == 0) {
                o.x = fmaxf(o.x, 0.f);
                o.y = fmaxf(o.y, 0.f);
                o.z = fmaxf(o.z, 0.f);
                o.w = fmaxf(o.w, 0.f);
            } else {
                o.x = 1.f / (1.f + __expf(-o.x));
                o.y = 1.f / (1.f + __expf(-o.y));
                o.z = 1.f / (1.f + __expf(-o.z));
                o.w = 1.f / (1.f + __expf(-o.w));
            }
            if (OUTB) {
                uint2 ob;
                ob.x = pack2bf(o.x, o.y);
                ob.y = pack2bf(o.z, o.w);
                *reinterpret_cast<uint2*>((uint*)xout + (size_t)row * (D / 2) + tx * 2) = ob;
            } else {
                *reinterpret_cast<float4*>((float*)xout + (size_t)row * D + j0) = o;
            }
        }
    }
}

extern "C" void kernel_launch(void* const* d_in, const int* in_sizes, int n_in,
                              void* d_out, int out_size, void* d_ws, size_t ws_size,
                              hipStream_t stream) {
    const float* x      = (const float*)d_in[0];
    const int*   ei     = (const int*)d_in[1];
    const float* ew     = (const float*)d_in[2];
    const float* W_self = (const float*)d_in[3];
    const float* W_neigh= (const float*)d_in[4];
    const float* bias   = (const float*)d_in[5];
    float* out = (float*)d_out;

    const int N = in_sizes[0] / D;
    const int E = in_sizes[2];
    const int L = in_sizes[5] / D;

    const int* src = ei;
    const int* dst = ei + E;

    char* p = (char*)d_ws;
    auto carve = [&](size_t bytes) -> void* {
        void* r = (void*)p;
        p += (bytes + 255) & ~(size_t)255;
        return r;
    };
    const int NB = (N + 511) / 512;
    int*   cnt       = (int*)carve((size_t)N * 4);
    int*   row_start = (int*)carve((size_t)N * 4);
    int*   cursor    = (int*)carve((size_t)N * 4);
    int*   partial   = (int*)carve((size_t)NB * 4);
    int*   blockoff  = (int*)carve((size_t)NB * 4);
    int2*  srcw      = (int2*)carve((size_t)E * 8);
    float* aggbuf    = (float*)carve((size_t)N * D * 4);
    uint*  xb        = (uint*)carve((size_t)N * (D / 2) * 4);  // bf16 x
    uint*  hb        = (uint*)carve((size_t)N * (D / 2) * 4);  // bf16 intermediate

    // ---- CSR build + x conversion ----
    hipMemsetAsync(cnt, 0, (size_t)N * 4, stream);
    k_convert<<<(N * D / 8 + 255) / 256, 256, 0, stream>>>(x, xb, N * D / 8);
    k_count<<<(E + 255) / 256, 256, 0, stream>>>(dst, E, cnt);
    k_scanA<<<NB, 256, 0, stream>>>(cnt, N, partial);
    k_scanB<<<1, 64, 0, stream>>>(partial, NB, blockoff);
    k_scanC<<<NB, 512, 0, stream>>>(cnt, N, blockoff, row_start, cursor);
    k_place<<<(E + 255) / 256, 256, 0, stream>>>(src, dst, ew, E, cursor, srcw);

    // ---- layers ----
    const int nblk_agg  = (N + 3) / 4;
    const int nblk_gemm = (N + 31) / 32;
    const uint* cur = xb;
    for (int l = 0; l < L; ++l) {
        const float* Wn = W_neigh + (size_t)l * D * D;
        const float* Ws = W_self  + (size_t)l * D * D;
        const float* bl = bias + (size_t)l * D;

        k_agg<<<nblk_agg, 256, 0, stream>>>(cur, srcw, row_start, cnt, aggbuf, N);
        if (l < L - 1) {
            k_gemm<0, 1><<<nblk_gemm, 256, 0, stream>>>(aggbuf, cur, Wn, Ws, bl, hb, N);
            cur = hb;
        } else {
            k_gemm<1, 0><<<nblk_gemm, 256, 0, stream>>>(aggbuf, cur, Wn, Ws, bl, out, N);
        }
    }
}

// Round 4
// 438.337 us; speedup vs baseline: 2.2998x; 1.2933x over previous
//
#include <hip/hip_runtime.h>
#include <math.h>

// GraphSAGE, 2 layers, N=100000, E=1.6M, D=128.
// CSR build; x,weights -> bf16 once. Per layer:
//   k_agg      : wave/node, 8 edge-slots x 8 col-groups, bf16 gathers, fp32 accum, bf16 out
//   k_gemm_mfma: [agg||x] @ WT (256-K bf16 MFMA), bias + act, no LDS

#define D 128

typedef unsigned int uint;
typedef __attribute__((ext_vector_type(8))) short short8;
typedef __attribute__((ext_vector_type(4))) float f32x4;

__device__ __forceinline__ float bf_lo(uint u) { return __uint_as_float(u << 16); }
__device__ __forceinline__ float bf_hi(uint u) { return __uint_as_float(u & 0xffff0000u); }
__device__ __forceinline__ unsigned short f2bf(float f) {
    uint u = __float_as_uint(f);
    u += 0x7fffu + ((u >> 16) & 1u);   // round-to-nearest-even
    return (unsigned short)(u >> 16);
}
__device__ __forceinline__ uint pack2bf(float lo, float hi) {
    return (uint)f2bf(lo) | ((uint)f2bf(hi) << 16);
}

// ---- fp32 -> bf16 conversion of x (8 elems/thread) ----
__global__ void k_convert(const float* __restrict__ in, uint* __restrict__ outb, int n8) {
    int i = blockIdx.x * 256 + threadIdx.x;
    if (i >= n8) return;
    const float4* p = reinterpret_cast<const float4*>(in + (size_t)i * 8);
    float4 a = p[0], b = p[1];
    uint4 o;
    o.x = pack2bf(a.x, a.y);
    o.y = pack2bf(a.z, a.w);
    o.z = pack2bf(b.x, b.y);
    o.w = pack2bf(b.z, b.w);
    reinterpret_cast<uint4*>(outb)[i] = o;
}

// ---- weights -> transposed concatenated bf16 table WT[l][j][k], k<128: Wn, else Ws
__global__ void k_wconv(const float* __restrict__ Wn, const float* __restrict__ Ws,
                        unsigned short* __restrict__ wt, int total) {
    int idx = blockIdx.x * 256 + threadIdx.x;
    if (idx >= total) return;
    int l = idx >> 15;           // 128*256 per layer
    int j = (idx >> 8) & 127;
    int k = idx & 255;
    float v = (k < 128) ? Wn[(size_t)l * 16384 + (size_t)k * 128 + j]
                        : Ws[(size_t)l * 16384 + (size_t)(k - 128) * 128 + j];
    wt[idx] = f2bf(v);
}

__global__ void k_count(const int* __restrict__ dst, int E, int* __restrict__ cnt) {
    int e = blockIdx.x * 256 + threadIdx.x;
    if (e < E) atomicAdd(&cnt[dst[e]], 1);
}

__global__ void k_scanA(const int* __restrict__ cnt, int N, int* __restrict__ partial) {
    __shared__ int s[256];
    int t = threadIdx.x;
    int base = blockIdx.x * 512;
    int v = 0;
    if (base + t < N) v += cnt[base + t];
    if (base + 256 + t < N) v += cnt[base + 256 + t];
    s[t] = v;
    __syncthreads();
    for (int off = 128; off > 0; off >>= 1) {
        if (t < off) s[t] += s[t + off];
        __syncthreads();
    }
    if (t == 0) partial[blockIdx.x] = s[0];
}

__global__ void k_scanB(const int* __restrict__ partial, int NB, int* __restrict__ blockoff) {
    if (threadIdx.x == 0 && blockIdx.x == 0) {
        int acc = 0;
        for (int b = 0; b < NB; ++b) { blockoff[b] = acc; acc += partial[b]; }
    }
}

__global__ void k_scanC(const int* __restrict__ cnt, int N, const int* __restrict__ blockoff,
                        int* __restrict__ row_start, int* __restrict__ cursor) {
    __shared__ int s[512];
    int t = threadIdx.x;
    int i = blockIdx.x * 512 + t;
    int v = (i < N) ? cnt[i] : 0;
    s[t] = v;
    __syncthreads();
    for (int off = 1; off < 512; off <<= 1) {
        int u = (t >= off) ? s[t - off] : 0;
        __syncthreads();
        s[t] += u;
        __syncthreads();
    }
    if (i < N) {
        int excl = blockoff[blockIdx.x] + s[t] - v;
        row_start[i] = excl;
        cursor[i] = excl;
    }
}

__global__ void k_place(const int* __restrict__ src, const int* __restrict__ dst,
                        const float* __restrict__ w, int E,
                        int* __restrict__ cursor, int2* __restrict__ srcw) {
    int e = blockIdx.x * 256 + threadIdx.x;
    if (e < E) {
        int d = dst[e];
        int p = atomicAdd(&cursor[d], 1);
        srcw[p] = make_int2(src[e], __float_as_int(w[e]));
    }
}

// One wave per node. lane = q*8 + c8: q = edge slot (8 concurrent edges),
// c8 = col group. Each lane gathers 2 uint4 (16 bf16) per edge.
__global__ __launch_bounds__(256, 4) void k_agg(
    const uint* __restrict__ xbf,          // bf16 features [N][64 uints]
    const int2* __restrict__ srcw,
    const int* __restrict__ row_start, const int* __restrict__ cnt,
    uint* __restrict__ agg, int N)         // bf16 out [N][64 uints]
{
    const int tid = threadIdx.x;
    const int wv = tid >> 6;
    const int lane = tid & 63;
    const int node = blockIdx.x * 4 + wv;
    if (node >= N) return;
    const int q = lane >> 3;
    const int c8 = lane & 7;
    const int st = row_start[node];
    const int num = cnt[node];
    const int en = st + num;

    float a[16];
#pragma unroll
    for (int j = 0; j < 16; ++j) a[j] = 0.f;

#pragma unroll 2
    for (int e = st + q; e < en; e += 8) {
        const int2 sw = srcw[e];
        const float w = __int_as_float(sw.y);
        const uint4* xr = reinterpret_cast<const uint4*>(xbf + (size_t)sw.x * 64);
        const uint4 v0 = xr[c8];
        const uint4 v1 = xr[c8 + 8];
        a[0]  = fmaf(w, bf_lo(v0.x), a[0]);  a[1]  = fmaf(w, bf_hi(v0.x), a[1]);
        a[2]  = fmaf(w, bf_lo(v0.y), a[2]);  a[3]  = fmaf(w, bf_hi(v0.y), a[3]);
        a[4]  = fmaf(w, bf_lo(v0.z), a[4]);  a[5]  = fmaf(w, bf_hi(v0.z), a[5]);
        a[6]  = fmaf(w, bf_lo(v0.w), a[6]);  a[7]  = fmaf(w, bf_hi(v0.w), a[7]);
        a[8]  = fmaf(w, bf_lo(v1.x), a[8]);  a[9]  = fmaf(w, bf_hi(v1.x), a[9]);
        a[10] = fmaf(w, bf_lo(v1.y), a[10]); a[11] = fmaf(w, bf_hi(v1.y), a[11]);
        a[12] = fmaf(w, bf_lo(v1.z), a[12]); a[13] = fmaf(w, bf_hi(v1.z), a[13]);
        a[14] = fmaf(w, bf_lo(v1.w), a[14]); a[15] = fmaf(w, bf_hi(v1.w), a[15]);
    }

#pragma unroll
    for (int j = 0; j < 16; ++j) {
        a[j] += __shfl_xor(a[j], 8);
        a[j] += __shfl_xor(a[j], 16);
        a[j] += __shfl_xor(a[j], 32);
    }

    if (q == 0) {
        const float invd = 1.0f / (float)(num > 1 ? num : 1);
        uint4 o0, o1;
        o0.x = pack2bf(a[0] * invd,  a[1] * invd);
        o0.y = pack2bf(a[2] * invd,  a[3] * invd);
        o0.z = pack2bf(a[4] * invd,  a[5] * invd);
        o0.w = pack2bf(a[6] * invd,  a[7] * invd);
        o1.x = pack2bf(a[8] * invd,  a[9] * invd);
        o1.y = pack2bf(a[10] * invd, a[11] * invd);
        o1.z = pack2bf(a[12] * invd, a[13] * invd);
        o1.w = pack2bf(a[14] * invd, a[15] * invd);
        uint4* ar = reinterpret_cast<uint4*>(agg + (size_t)node * 64);
        ar[c8] = o0;
        ar[c8 + 8] = o1;
    }
}

// MFMA GEMM: out[row][col] = sum_k [agg||x][row][k] * WT[col][k] + bias[col], act.
// 64 rows/block, 4 waves as 2(m) x 2(n); per wave: 2 mtiles x 4 ntiles of 16x16.
// A-frags from global (each row read once per block), B-frags from L2-resident WT.
// ACT: 0 relu, 1 sigmoid. OUTB: 1 bf16 out, 0 fp32 out.
template <int ACT, int OUTB>
__global__ __launch_bounds__(256) void k_gemm_mfma(
    const uint* __restrict__ aggb, const uint* __restrict__ xb,
    const uint* __restrict__ wt,   // bf16 WT [128 cols][256 k] = [128][128 uints]
    const float* __restrict__ bias, void* __restrict__ xout, int N)
{
    const int tid = threadIdx.x;
    const int lane = tid & 63;
    const int wv = tid >> 6;
    const int wm = wv >> 1, wn = wv & 1;
    const int l16 = lane & 15;
    const int lq = lane >> 4;              // 0..3
    const int rowbase = blockIdx.x * 64 + wm * 32;
    const int colbase = wn * 64;

    // ---- load A fragments: lane holds A[row=l16][k = kk*32 + lq*8 .. +7]
    short8 afrag[2][8];
#pragma unroll
    for (int mt = 0; mt < 2; ++mt) {
        int row = rowbase + mt * 16 + l16;
        if (row >= N) row = N - 1;
        const uint* arow = aggb + (size_t)row * 64;
        const uint* xrow = xb + (size_t)row * 64;
#pragma unroll
        for (int kk = 0; kk < 8; ++kk) {
            const uint* srcrow = (kk < 4) ? arow : xrow;
            uint4 u = *reinterpret_cast<const uint4*>(srcrow + (kk & 3) * 16 + lq * 4);
            afrag[mt][kk] = *reinterpret_cast<short8*>(&u);
        }
    }

#pragma unroll
    for (int nt = 0; nt < 4; ++nt) {
        const int col = colbase + nt * 16 + l16;
        const uint* wrow = wt + (size_t)col * 128;
        f32x4 acc0 = {0.f, 0.f, 0.f, 0.f};
        f32x4 acc1 = {0.f, 0.f, 0.f, 0.f};
#pragma unroll
        for (int kk = 0; kk < 8; ++kk) {
            uint4 u = *reinterpret_cast<const uint4*>(wrow + kk * 16 + lq * 4);
            short8 bfrag = *reinterpret_cast<short8*>(&u);
            acc0 = __builtin_amdgcn_mfma_f32_16x16x32_bf16(afrag[0][kk], bfrag, acc0, 0, 0, 0);
            acc1 = __builtin_amdgcn_mfma_f32_16x16x32_bf16(afrag[1][kk], bfrag, acc1, 0, 0, 0);
        }
        const float bv = bias[col];
#pragma unroll
        for (int mt = 0; mt < 2; ++mt) {
            const f32x4 acc = mt ? acc1 : acc0;
#pragma unroll
            for (int r = 0; r < 4; ++r) {
                int row = rowbase + mt * 16 + lq * 4 + r;
                if (row < N) {
                    float v = acc[r] + bv;
                    if (ACT == 0) v = fmaxf(v, 0.f);
                    else          v = 1.f / (1.f + __expf(-v));
                    if (OUTB) ((unsigned short*)xout)[(size_t)row * D + col] = f2bf(v);
                    else      ((float*)xout)[(size_t)row * D + col] = v;
                }
            }
        }
    }
}

extern "C" void kernel_launch(void* const* d_in, const int* in_sizes, int n_in,
                              void* d_out, int out_size, void* d_ws, size_t ws_size,
                              hipStream_t stream) {
    const float* x      = (const float*)d_in[0];
    const int*   ei     = (const int*)d_in[1];
    const float* ew     = (const float*)d_in[2];
    const float* W_self = (const float*)d_in[3];
    const float* W_neigh= (const float*)d_in[4];
    const float* bias   = (const float*)d_in[5];
    float* out = (float*)d_out;

    const int N = in_sizes[0] / D;
    const int E = in_sizes[2];
    const int L = in_sizes[5] / D;

    const int* src = ei;
    const int* dst = ei + E;

    char* p = (char*)d_ws;
    auto carve = [&](size_t bytes) -> void* {
        void* r = (void*)p;
        p += (bytes + 255) & ~(size_t)255;
        return r;
    };
    const int NB = (N + 511) / 512;
    int*   cnt       = (int*)carve((size_t)N * 4);
    int*   row_start = (int*)carve((size_t)N * 4);
    int*   cursor    = (int*)carve((size_t)N * 4);
    int*   partial   = (int*)carve((size_t)NB * 4);
    int*   blockoff  = (int*)carve((size_t)NB * 4);
    int2*  srcw      = (int2*)carve((size_t)E * 8);
    uint*  xb        = (uint*)carve((size_t)N * (D / 2) * 4);   // bf16 x
    uint*  aggb      = (uint*)carve((size_t)N * (D / 2) * 4);   // bf16 agg
    uint*  hb        = (uint*)carve((size_t)N * (D / 2) * 4);   // bf16 intermediate
    uint*  wtbl      = (uint*)carve((size_t)L * 128 * 128 * 4); // bf16 WT

    // ---- precompute: bf16 conversions + CSR build ----
    hipMemsetAsync(cnt, 0, (size_t)N * 4, stream);
    k_convert<<<(N * D / 8 + 255) / 256, 256, 0, stream>>>(x, xb, N * D / 8);
    k_wconv<<<(L * 32768 + 255) / 256, 256, 0, stream>>>(W_neigh, W_self,
                                                         (unsigned short*)wtbl, L * 32768);
    k_count<<<(E + 255) / 256, 256, 0, stream>>>(dst, E, cnt);
    k_scanA<<<NB, 256, 0, stream>>>(cnt, N, partial);
    k_scanB<<<1, 64, 0, stream>>>(partial, NB, blockoff);
    k_scanC<<<NB, 512, 0, stream>>>(cnt, N, blockoff, row_start, cursor);
    k_place<<<(E + 255) / 256, 256, 0, stream>>>(src, dst, ew, E, cursor, srcw);

    // ---- layers ----
    const int nblk_agg  = (N + 3) / 4;
    const int nblk_gemm = (N + 63) / 64;
    const uint* cur = xb;
    for (int l = 0; l < L; ++l) {
        const uint* wtl = wtbl + (size_t)l * 128 * 128;
        const float* bl = bias + (size_t)l * D;

        k_agg<<<nblk_agg, 256, 0, stream>>>(cur, srcw, row_start, cnt, aggb, N);
        if (l < L - 1) {
            k_gemm_mfma<0, 1><<<nblk_gemm, 256, 0, stream>>>(aggb, cur, wtl, bl, hb, N);
            cur = hb;
        } else {
            k_gemm_mfma<1, 0><<<nblk_gemm, 256, 0, stream>>>(aggb, cur, wtl, bl, out, N);
        }
    }
}

// Round 5
// 304.038 us; speedup vs baseline: 3.3157x; 1.4417x over previous
//
#include <hip/hip_runtime.h>
#include <math.h>

// GraphSAGE, 2 layers, N=100000, E=1.6M, D=128.
// Bucketed counting-sort CSR build (XCD-write-locality), bf16 features/weights,
// per layer: k_agg (wave/node bf16 gathers, fp32 accum) -> k_gemm_mfma.

#define D 128
#define BK_SHIFT 9
#define BK_NODES 512
#define CH1 4096

typedef unsigned int uint;
typedef unsigned short ushort;
typedef __attribute__((ext_vector_type(8))) short short8;
typedef __attribute__((ext_vector_type(4))) float f32x4;

__device__ __forceinline__ float bf_lo(uint u) { return __uint_as_float(u << 16); }
__device__ __forceinline__ float bf_hi(uint u) { return __uint_as_float(u & 0xffff0000u); }
__device__ __forceinline__ ushort f2bf(float f) {
    uint u = __float_as_uint(f);
    u += 0x7fffu + ((u >> 16) & 1u);   // round-to-nearest-even
    return (ushort)(u >> 16);
}
__device__ __forceinline__ uint pack2bf(float lo, float hi) {
    return (uint)f2bf(lo) | ((uint)f2bf(hi) << 16);
}

// ---- fp32 -> bf16 conversion of x (8 elems/thread) ----
__global__ void k_convert(const float* __restrict__ in, uint* __restrict__ outb, int n8) {
    int i = blockIdx.x * 256 + threadIdx.x;
    if (i >= n8) return;
    const float4* p = reinterpret_cast<const float4*>(in + (size_t)i * 8);
    float4 a = p[0], b = p[1];
    uint4 o;
    o.x = pack2bf(a.x, a.y);
    o.y = pack2bf(a.z, a.w);
    o.z = pack2bf(b.x, b.y);
    o.w = pack2bf(b.z, b.w);
    reinterpret_cast<uint4*>(outb)[i] = o;
}

// ---- weights -> transposed concatenated bf16 WT[l][j][k], k<128: Wn, else Ws
__global__ void k_wconv(const float* __restrict__ Wn, const float* __restrict__ Ws,
                        ushort* __restrict__ wt, int total) {
    int idx = blockIdx.x * 256 + threadIdx.x;
    if (idx >= total) return;
    int l = idx >> 15;
    int j = (idx >> 8) & 127;
    int k = idx & 255;
    float v = (k < 128) ? Wn[(size_t)l * 16384 + (size_t)k * 128 + j]
                        : Ws[(size_t)l * 16384 + (size_t)(k - 128) * 128 + j];
    wt[idx] = f2bf(v);
}

// ---- bucket histogram: bh[b] = #edges with dst in bucket b ----
__global__ __launch_bounds__(256) void k_bhist(const int* __restrict__ dst, int E,
                                               int* __restrict__ bh) {
    __shared__ int h[256];
    const int t = threadIdx.x;
    h[t] = 0;
    __syncthreads();
    const int base = blockIdx.x * 8192;
    for (int j = 0; j < 32; ++j) {
        int i = base + j * 256 + t;
        if (i < E) atomicAdd(&h[dst[i] >> BK_SHIFT], 1);
    }
    __syncthreads();
    if (h[t] > 0) atomicAdd(&bh[t], h[t]);
}

// ---- bucket scan: base/cursor init, rs sentinel ----
__global__ void k_bscan(const int* __restrict__ bh, int B, int E,
                        int* __restrict__ base, int* __restrict__ cursor,
                        int* __restrict__ rs, int N) {
    if (threadIdx.x == 0 && blockIdx.x == 0) {
        int acc = 0;
        for (int b = 0; b < B; ++b) { base[b] = acc; cursor[b] = acc; acc += bh[b]; }
        base[B] = acc;
        rs[N] = E;
    }
}

// ---- phase 1: bin edges into bucket-ordered bpk/bw ----
__global__ __launch_bounds__(256) void k_sort1(
    const int* __restrict__ src, const int* __restrict__ dst, const float* __restrict__ w,
    int E, int* __restrict__ cursor,
    uint* __restrict__ bpk, float* __restrict__ bw)
{
    __shared__ int h[256];
    __shared__ int gbase[256];
    const int t = threadIdx.x;
    h[t] = 0;
    __syncthreads();
    const int base0 = blockIdx.x * CH1;
    uint pk[16]; float wr[16]; int br[16];
#pragma unroll
    for (int j = 0; j < 16; ++j) {
        int i = base0 + j * 256 + t;
        br[j] = -1;
        if (i < E) {
            int d = dst[i];
            int b = d >> BK_SHIFT;
            int r = atomicAdd(&h[b], 1);
            pk[j] = (uint)src[i] | ((uint)(d & (BK_NODES - 1)) << 17);
            wr[j] = w[i];
            br[j] = (b << 16) | r;
        }
    }
    __syncthreads();
    if (h[t] > 0) gbase[t] = atomicAdd(&cursor[t], h[t]);
    __syncthreads();
#pragma unroll
    for (int j = 0; j < 16; ++j) {
        if (br[j] >= 0) {
            int b = br[j] >> 16, r = br[j] & 0xffff;
            int g = gbase[b] + r;
            bpk[g] = pk[j];
            bw[g] = wr[j];
        }
    }
}

// ---- phase 2: per bucket, build row_start + place (src,w) into CSR window ----
__global__ __launch_bounds__(512) void k_sort2(
    const uint* __restrict__ bpk, const float* __restrict__ bw,
    const int* __restrict__ base, int N,
    int* __restrict__ rs, int2* __restrict__ srcw)
{
    __shared__ int h[512];
    __shared__ int sa[512];
    __shared__ int sb[512];
    __shared__ int cur[512];
    const int t = threadIdx.x;
    const int b = blockIdx.x;
    const int gb = base[b];
    const int cnt = base[b + 1] - gb;
    const int lo = b * BK_NODES;
    h[t] = 0;
    __syncthreads();
    for (int i = t; i < cnt; i += 512) {
        uint p = bpk[gb + i];
        atomicAdd(&h[(p >> 17) & 511], 1);
    }
    __syncthreads();
    sa[t] = h[t];
    __syncthreads();
    int* sin = sa; int* sout = sb;
    for (int off = 1; off < 512; off <<= 1) {
        int v = sin[t];
        if (t >= off) v += sin[t - off];
        sout[t] = v;
        __syncthreads();
        int* tmp = sin; sin = sout; sout = tmp;
    }
    const int ex = sin[t] - h[t];      // exclusive scan
    cur[t] = ex;
    if (lo + t < N) rs[lo + t] = gb + ex;
    __syncthreads();
    for (int i = t; i < cnt; i += 512) {
        uint p = bpk[gb + i];
        float wv = bw[gb + i];
        int n9 = (p >> 17) & 511;
        int off = atomicAdd(&cur[n9], 1);
        srcw[gb + off] = make_int2((int)(p & 0x1FFFFu), __float_as_int(wv));
    }
}

// One wave per node. lane = q*8 + c8: q = edge slot (8 concurrent edges),
// c8 = col group. Each lane gathers 2 uint4 (16 bf16) per edge.
__global__ __launch_bounds__(256, 4) void k_agg(
    const uint* __restrict__ xbf,
    const int2* __restrict__ srcw,
    const int* __restrict__ rs,
    uint* __restrict__ agg, int N)
{
    const int tid = threadIdx.x;
    const int wv = tid >> 6;
    const int lane = tid & 63;
    const int node = blockIdx.x * 4 + wv;
    if (node >= N) return;
    const int q = lane >> 3;
    const int c8 = lane & 7;
    const int st = rs[node];
    const int num = rs[node + 1] - st;
    const int en = st + num;

    float a[16];
#pragma unroll
    for (int j = 0; j < 16; ++j) a[j] = 0.f;

#pragma unroll 2
    for (int e = st + q; e < en; e += 8) {
        const int2 sw = srcw[e];
        const float w = __int_as_float(sw.y);
        const uint4* xr = reinterpret_cast<const uint4*>(xbf + (size_t)sw.x * 64);
        const uint4 v0 = xr[c8];
        const uint4 v1 = xr[c8 + 8];
        a[0]  = fmaf(w, bf_lo(v0.x), a[0]);  a[1]  = fmaf(w, bf_hi(v0.x), a[1]);
        a[2]  = fmaf(w, bf_lo(v0.y), a[2]);  a[3]  = fmaf(w, bf_hi(v0.y), a[3]);
        a[4]  = fmaf(w, bf_lo(v0.z), a[4]);  a[5]  = fmaf(w, bf_hi(v0.z), a[5]);
        a[6]  = fmaf(w, bf_lo(v0.w), a[6]);  a[7]  = fmaf(w, bf_hi(v0.w), a[7]);
        a[8]  = fmaf(w, bf_lo(v1.x), a[8]);  a[9]  = fmaf(w, bf_hi(v1.x), a[9]);
        a[10] = fmaf(w, bf_lo(v1.y), a[10]); a[11] = fmaf(w, bf_hi(v1.y), a[11]);
        a[12] = fmaf(w, bf_lo(v1.z), a[12]); a[13] = fmaf(w, bf_hi(v1.z), a[13]);
        a[14] = fmaf(w, bf_lo(v1.w), a[14]); a[15] = fmaf(w, bf_hi(v1.w), a[15]);
    }

#pragma unroll
    for (int j = 0; j < 16; ++j) {
        a[j] += __shfl_xor(a[j], 8);
        a[j] += __shfl_xor(a[j], 16);
        a[j] += __shfl_xor(a[j], 32);
    }

    if (q == 0) {
        const float invd = 1.0f / (float)(num > 1 ? num : 1);
        uint4 o0, o1;
        o0.x = pack2bf(a[0] * invd,  a[1] * invd);
        o0.y = pack2bf(a[2] * invd,  a[3] * invd);
        o0.z = pack2bf(a[4] * invd,  a[5] * invd);
        o0.w = pack2bf(a[6] * invd,  a[7] * invd);
        o1.x = pack2bf(a[8] * invd,  a[9] * invd);
        o1.y = pack2bf(a[10] * invd, a[11] * invd);
        o1.z = pack2bf(a[12] * invd, a[13] * invd);
        o1.w = pack2bf(a[14] * invd, a[15] * invd);
        uint4* ar = reinterpret_cast<uint4*>(agg + (size_t)node * 64);
        ar[c8] = o0;
        ar[c8 + 8] = o1;
    }
}

// MFMA GEMM: out = [agg||x] @ WT + bias, act. 64 rows/block, 4 waves 2x2.
template <int ACT, int OUTB>
__global__ __launch_bounds__(256) void k_gemm_mfma(
    const uint* __restrict__ aggb, const uint* __restrict__ xb,
    const uint* __restrict__ wt,
    const float* __restrict__ bias, void* __restrict__ xout, int N)
{
    const int tid = threadIdx.x;
    const int lane = tid & 63;
    const int wv = tid >> 6;
    const int wm = wv >> 1, wn = wv & 1;
    const int l16 = lane & 15;
    const int lq = lane >> 4;
    const int rowbase = blockIdx.x * 64 + wm * 32;
    const int colbase = wn * 64;

    short8 afrag[2][8];
#pragma unroll
    for (int mt = 0; mt < 2; ++mt) {
        int row = rowbase + mt * 16 + l16;
        if (row >= N) row = N - 1;
        const uint* arow = aggb + (size_t)row * 64;
        const uint* xrow = xb + (size_t)row * 64;
#pragma unroll
        for (int kk = 0; kk < 8; ++kk) {
            const uint* srcrow = (kk < 4) ? arow : xrow;
            uint4 u = *reinterpret_cast<const uint4*>(srcrow + (kk & 3) * 16 + lq * 4);
            afrag[mt][kk] = *reinterpret_cast<short8*>(&u);
        }
    }

#pragma unroll
    for (int nt = 0; nt < 4; ++nt) {
        const int col = colbase + nt * 16 + l16;
        const uint* wrow = wt + (size_t)col * 128;
        f32x4 acc0 = {0.f, 0.f, 0.f, 0.f};
        f32x4 acc1 = {0.f, 0.f, 0.f, 0.f};
#pragma unroll
        for (int kk = 0; kk < 8; ++kk) {
            uint4 u = *reinterpret_cast<const uint4*>(wrow + kk * 16 + lq * 4);
            short8 bfrag = *reinterpret_cast<short8*>(&u);
            acc0 = __builtin_amdgcn_mfma_f32_16x16x32_bf16(afrag[0][kk], bfrag, acc0, 0, 0, 0);
            acc1 = __builtin_amdgcn_mfma_f32_16x16x32_bf16(afrag[1][kk], bfrag, acc1, 0, 0, 0);
        }
        const float bv = bias[col];
#pragma unroll
        for (int mt = 0; mt < 2; ++mt) {
            const f32x4 acc = mt ? acc1 : acc0;
#pragma unroll
            for (int r = 0; r < 4; ++r) {
                int row = rowbase + mt * 16 + lq * 4 + r;
                if (row < N) {
                    float v = acc[r] + bv;
                    if (ACT == 0) v = fmaxf(v, 0.f);
                    else          v = 1.f / (1.f + __expf(-v));
                    if (OUTB) ((ushort*)xout)[(size_t)row * D + col] = f2bf(v);
                    else      ((float*)xout)[(size_t)row * D + col] = v;
                }
            }
        }
    }
}

extern "C" void kernel_launch(void* const* d_in, const int* in_sizes, int n_in,
                              void* d_out, int out_size, void* d_ws, size_t ws_size,
                              hipStream_t stream) {
    const float* x      = (const float*)d_in[0];
    const int*   ei     = (const int*)d_in[1];
    const float* ew     = (const float*)d_in[2];
    const float* W_self = (const float*)d_in[3];
    const float* W_neigh= (const float*)d_in[4];
    const float* bias   = (const float*)d_in[5];
    float* out = (float*)d_out;

    const int N = in_sizes[0] / D;
    const int E = in_sizes[2];
    const int L = in_sizes[5] / D;
    const int B = (N + BK_NODES - 1) >> BK_SHIFT;

    const int* src = ei;
    const int* dst = ei + E;

    char* p = (char*)d_ws;
    auto carve = [&](size_t bytes) -> void* {
        void* r = (void*)p;
        p += (bytes + 255) & ~(size_t)255;
        return r;
    };
    int*   bh     = (int*)carve(256 * 4);
    int*   bbase  = (int*)carve((size_t)(B + 1) * 4);
    int*   bcur   = (int*)carve(256 * 4);
    int*   rs     = (int*)carve((size_t)(N + 1) * 4);
    uint*  bpk    = (uint*)carve((size_t)E * 4);
    float* bw     = (float*)carve((size_t)E * 4);
    int2*  srcw   = (int2*)carve((size_t)E * 8);
    uint*  xb     = (uint*)carve((size_t)N * (D / 2) * 4);
    uint*  aggb   = (uint*)carve((size_t)N * (D / 2) * 4);
    uint*  hb     = (uint*)carve((size_t)N * (D / 2) * 4);
    uint*  wtbl   = (uint*)carve((size_t)L * 128 * 128 * 4);

    // ---- precompute ----
    hipMemsetAsync(bh, 0, 256 * 4, stream);
    k_convert<<<(N * D / 8 + 255) / 256, 256, 0, stream>>>(x, xb, N * D / 8);
    k_wconv<<<(L * 32768 + 255) / 256, 256, 0, stream>>>(W_neigh, W_self,
                                                         (ushort*)wtbl, L * 32768);
    k_bhist<<<(E + 8191) / 8192, 256, 0, stream>>>(dst, E, bh);
    k_bscan<<<1, 64, 0, stream>>>(bh, B, E, bbase, bcur, rs, N);
    k_sort1<<<(E + CH1 - 1) / CH1, 256, 0, stream>>>(src, dst, ew, E, bcur, bpk, bw);
    k_sort2<<<B, 512, 0, stream>>>(bpk, bw, bbase, N, rs, srcw);

    // ---- layers ----
    const int nblk_agg  = (N + 3) / 4;
    const int nblk_gemm = (N + 63) / 64;
    const uint* cur = xb;
    for (int l = 0; l < L; ++l) {
        const uint* wtl = wtbl + (size_t)l * 128 * 128;
        const float* bl = bias + (size_t)l * D;

        k_agg<<<nblk_agg, 256, 0, stream>>>(cur, srcw, rs, aggb, N);
        if (l < L - 1) {
            k_gemm_mfma<0, 1><<<nblk_gemm, 256, 0, stream>>>(aggb, cur, wtl, bl, hb, N);
            cur = hb;
        } else {
            k_gemm_mfma<1, 0><<<nblk_gemm, 256, 0, stream>>>(aggb, cur, wtl, bl, out, N);
        }
    }
}

// Round 6
// 267.182 us; speedup vs baseline: 3.7730x; 1.1379x over previous
//
#include <hip/hip_runtime.h>
#include <math.h>

// GraphSAGE, 2 layers, N=100000, E=1.6M, D=128.
// Bucket-padded counting-sort CSR (no global scan), bf16 features/weights.
// k_prep (convert x + convert W + bin edges) -> k_sort2 (per-bucket CSR)
// -> per layer: k_agg (packed-fma bf16 gathers) -> k_gemm_mfma.

#define D 128
#define BK_SHIFT 9
#define BK_NODES 512
#define CAP 10240
#define CH1 4096

typedef unsigned int uint;
typedef unsigned short ushort;
typedef __attribute__((ext_vector_type(8))) short short8;
typedef __attribute__((ext_vector_type(4))) float f32x4;
typedef __attribute__((ext_vector_type(2))) float f32x2;

__device__ __forceinline__ float bf_lo(uint u) { return __uint_as_float(u << 16); }
__device__ __forceinline__ float bf_hi(uint u) { return __uint_as_float(u & 0xffff0000u); }
__device__ __forceinline__ ushort f2bf(float f) {
    uint u = __float_as_uint(f);
    u += 0x7fffu + ((u >> 16) & 1u);   // round-to-nearest-even
    return (ushort)(u >> 16);
}
__device__ __forceinline__ uint pack2bf(float lo, float hi) {
    return (uint)f2bf(lo) | ((uint)f2bf(hi) << 16);
}

// Fused prep: [0,nbConv): x->bf16; [nbConv,nbConv+nbW): weights->WT bf16;
// rest: bin edges into bucket-padded bedge with per-bucket cursors.
__global__ __launch_bounds__(256) void k_prep(
    const float* __restrict__ x, uint* __restrict__ xb, int n8,
    const float* __restrict__ Wn, const float* __restrict__ Ws,
    ushort* __restrict__ wt, int wtotal,
    const int* __restrict__ src, const int* __restrict__ dst,
    const float* __restrict__ w, int E,
    int* __restrict__ bcur, int2* __restrict__ bedge,
    int nbConv, int nbW)
{
    __shared__ int h[256];
    __shared__ int gbase[256];
    const int t = threadIdx.x;
    const int bid = blockIdx.x;

    if (bid < nbConv) {
        int i = bid * 256 + t;
        if (i >= n8) return;
        const float4* p = reinterpret_cast<const float4*>(x + (size_t)i * 8);
        float4 a = p[0], b = p[1];
        uint4 o;
        o.x = pack2bf(a.x, a.y);
        o.y = pack2bf(a.z, a.w);
        o.z = pack2bf(b.x, b.y);
        o.w = pack2bf(b.z, b.w);
        reinterpret_cast<uint4*>(xb)[i] = o;
        return;
    }
    if (bid < nbConv + nbW) {
        int idx = (bid - nbConv) * 256 + t;
        if (idx >= wtotal) return;
        int l = idx >> 15;
        int j = (idx >> 8) & 127;
        int k = idx & 255;
        float v = (k < 128) ? Wn[(size_t)l * 16384 + (size_t)k * 128 + j]
                            : Ws[(size_t)l * 16384 + (size_t)(k - 128) * 128 + j];
        wt[idx] = f2bf(v);
        return;
    }

    // ---- edge binning ----
    h[t] = 0;
    __syncthreads();
    const int base0 = (bid - nbConv - nbW) * CH1;
    uint pk[16]; float wr[16]; int br[16];
#pragma unroll
    for (int j = 0; j < 16; ++j) {
        int i = base0 + j * 256 + t;
        br[j] = -1;
        if (i < E) {
            int d = dst[i];
            int b = d >> BK_SHIFT;
            int r = atomicAdd(&h[b], 1);
            pk[j] = (uint)src[i] | ((uint)(d & (BK_NODES - 1)) << 17);
            wr[j] = w[i];
            br[j] = (b << 16) | r;
        }
    }
    __syncthreads();
    if (h[t] > 0) gbase[t] = atomicAdd(&bcur[t], h[t]);
    __syncthreads();
#pragma unroll
    for (int j = 0; j < 16; ++j) {
        if (br[j] >= 0) {
            int b = br[j] >> 16, r = br[j] & 0xffff;
            int slot = gbase[b] + r;
            if (slot < CAP)
                bedge[(size_t)b * CAP + slot] = make_int2((int)pk[j], __float_as_int(wr[j]));
        }
    }
}

// Per bucket: group edges by node -> padded CSR window + rsdeg = {start, deg}.
__global__ __launch_bounds__(512) void k_sort2(
    const int2* __restrict__ bedge, const int* __restrict__ bcnt,
    int N, int2* __restrict__ rsdeg, int2* __restrict__ srcw)
{
    __shared__ int h[512];
    __shared__ int sa[512];
    __shared__ int sb[512];
    __shared__ int cur[512];
    const int t = threadIdx.x;
    const int b = blockIdx.x;
    const int gb = b * CAP;
    int cnt = bcnt[b];
    if (cnt > CAP) cnt = CAP;
    const int lo = b * BK_NODES;
    h[t] = 0;
    __syncthreads();
    for (int i = t; i < cnt; i += 512) {
        atomicAdd(&h[((uint)bedge[gb + i].x >> 17) & 511], 1);
    }
    __syncthreads();
    sa[t] = h[t];
    __syncthreads();
    int* sin = sa; int* sout = sb;
    for (int off = 1; off < 512; off <<= 1) {
        int v = sin[t];
        if (t >= off) v += sin[t - off];
        sout[t] = v;
        __syncthreads();
        int* tmp = sin; sin = sout; sout = tmp;
    }
    const int ex = sin[t] - h[t];      // exclusive within-bucket
    cur[t] = ex;
    if (lo + t < N) rsdeg[lo + t] = make_int2(gb + ex, h[t]);
    __syncthreads();
    for (int i = t; i < cnt; i += 512) {
        int2 pe = bedge[gb + i];
        int n9 = ((uint)pe.x >> 17) & 511;
        int off = atomicAdd(&cur[n9], 1);
        srcw[gb + off] = make_int2(pe.x & 0x1FFFF, pe.y);
    }
}

// One wave per node. lane = q*16 + c16: q = edge slot (4 concurrent edges),
// c16 = 8-col group. Each lane gathers 1 uint4 (8 bf16) per edge; packed fma.
__global__ __launch_bounds__(256, 8) void k_agg(
    const uint* __restrict__ xbf,
    const int2* __restrict__ srcw,
    const int2* __restrict__ rsdeg,
    uint* __restrict__ agg, int N)
{
    const int tid = threadIdx.x;
    const int wv = tid >> 6;
    const int lane = tid & 63;
    const int node = blockIdx.x * 4 + wv;
    if (node >= N) return;
    const int q = lane >> 4;
    const int c16 = lane & 15;
    const int2 rd = rsdeg[node];
    const int st = rd.x;
    const int num = rd.y;
    const int en = st + num;

    f32x2 a2[4];
#pragma unroll
    for (int j = 0; j < 4; ++j) a2[j] = (f32x2){0.f, 0.f};

#pragma unroll 4
    for (int e = st + q; e < en; e += 4) {
        const int2 sw = srcw[e];
        const float wv_ = __int_as_float(sw.y);
        const f32x2 w2 = {wv_, wv_};
        const uint4 v = reinterpret_cast<const uint4*>(xbf + (size_t)sw.x * 64)[c16];
        f32x2 p0 = {bf_lo(v.x), bf_hi(v.x)};
        f32x2 p1 = {bf_lo(v.y), bf_hi(v.y)};
        f32x2 p2 = {bf_lo(v.z), bf_hi(v.z)};
        f32x2 p3 = {bf_lo(v.w), bf_hi(v.w)};
        a2[0] = __builtin_elementwise_fma(w2, p0, a2[0]);
        a2[1] = __builtin_elementwise_fma(w2, p1, a2[1]);
        a2[2] = __builtin_elementwise_fma(w2, p2, a2[2]);
        a2[3] = __builtin_elementwise_fma(w2, p3, a2[3]);
    }

    float a[8];
    a[0] = a2[0].x; a[1] = a2[0].y;
    a[2] = a2[1].x; a[3] = a2[1].y;
    a[4] = a2[2].x; a[5] = a2[2].y;
    a[6] = a2[3].x; a[7] = a2[3].y;
#pragma unroll
    for (int j = 0; j < 8; ++j) {
        a[j] += __shfl_xor(a[j], 16);
        a[j] += __shfl_xor(a[j], 32);
    }

    if (q == 0) {
        const float invd = 1.0f / (float)(num > 1 ? num : 1);
        uint4 o;
        o.x = pack2bf(a[0] * invd, a[1] * invd);
        o.y = pack2bf(a[2] * invd, a[3] * invd);
        o.z = pack2bf(a[4] * invd, a[5] * invd);
        o.w = pack2bf(a[6] * invd, a[7] * invd);
        reinterpret_cast<uint4*>(agg + (size_t)node * 64)[c16] = o;
    }
}

// MFMA GEMM: out = [agg||x] @ WT + bias, act. 64 rows/block, 4 waves 2x2.
template <int ACT, int OUTB>
__global__ __launch_bounds__(256) void k_gemm_mfma(
    const uint* __restrict__ aggb, const uint* __restrict__ xb,
    const uint* __restrict__ wt,
    const float* __restrict__ bias, void* __restrict__ xout, int N)
{
    const int tid = threadIdx.x;
    const int lane = tid & 63;
    const int wv = tid >> 6;
    const int wm = wv >> 1, wn = wv & 1;
    const int l16 = lane & 15;
    const int lq = lane >> 4;
    const int rowbase = blockIdx.x * 64 + wm * 32;
    const int colbase = wn * 64;

    short8 afrag[2][8];
#pragma unroll
    for (int mt = 0; mt < 2; ++mt) {
        int row = rowbase + mt * 16 + l16;
        if (row >= N) row = N - 1;
        const uint* arow = aggb + (size_t)row * 64;
        const uint* xrow = xb + (size_t)row * 64;
#pragma unroll
        for (int kk = 0; kk < 8; ++kk) {
            const uint* srcrow = (kk < 4) ? arow : xrow;
            uint4 u = *reinterpret_cast<const uint4*>(srcrow + (kk & 3) * 16 + lq * 4);
            afrag[mt][kk] = *reinterpret_cast<short8*>(&u);
        }
    }

#pragma unroll
    for (int nt = 0; nt < 4; ++nt) {
        const int col = colbase + nt * 16 + l16;
        const uint* wrow = wt + (size_t)col * 128;
        f32x4 acc0 = {0.f, 0.f, 0.f, 0.f};
        f32x4 acc1 = {0.f, 0.f, 0.f, 0.f};
#pragma unroll
        for (int kk = 0; kk < 8; ++kk) {
            uint4 u = *reinterpret_cast<const uint4*>(wrow + kk * 16 + lq * 4);
            short8 bfrag = *reinterpret_cast<short8*>(&u);
            acc0 = __builtin_amdgcn_mfma_f32_16x16x32_bf16(afrag[0][kk], bfrag, acc0, 0, 0, 0);
            acc1 = __builtin_amdgcn_mfma_f32_16x16x32_bf16(afrag[1][kk], bfrag, acc1, 0, 0, 0);
        }
        const float bv = bias[col];
#pragma unroll
        for (int mt = 0; mt < 2; ++mt) {
            const f32x4 acc = mt ? acc1 : acc0;
#pragma unroll
            for (int r = 0; r < 4; ++r) {
                int row = rowbase + mt * 16 + lq * 4 + r;
                if (row < N) {
                    float v = acc[r] + bv;
                    if (ACT == 0) v = fmaxf(v, 0.f);
                    else          v = 1.f / (1.f + __expf(-v));
                    if (OUTB) ((ushort*)xout)[(size_t)row * D + col] = f2bf(v);
                    else      ((float*)xout)[(size_t)row * D + col] = v;
                }
            }
        }
    }
}

extern "C" void kernel_launch(void* const* d_in, const int* in_sizes, int n_in,
                              void* d_out, int out_size, void* d_ws, size_t ws_size,
                              hipStream_t stream) {
    const float* x      = (const float*)d_in[0];
    const int*   ei     = (const int*)d_in[1];
    const float* ew     = (const float*)d_in[2];
    const float* W_self = (const float*)d_in[3];
    const float* W_neigh= (const float*)d_in[4];
    const float* bias   = (const float*)d_in[5];
    float* out = (float*)d_out;

    const int N = in_sizes[0] / D;
    const int E = in_sizes[2];
    const int L = in_sizes[5] / D;
    const int B = (N + BK_NODES - 1) >> BK_SHIFT;

    const int* src = ei;
    const int* dst = ei + E;

    char* p = (char*)d_ws;
    auto carve = [&](size_t bytes) -> void* {
        void* r = (void*)p;
        p += (bytes + 255) & ~(size_t)255;
        return r;
    };
    int*   bcur   = (int*)carve(256 * 4);
    int2*  bedge  = (int2*)carve((size_t)B * CAP * 8);
    int2*  srcw   = (int2*)carve((size_t)B * CAP * 8);
    int2*  rsdeg  = (int2*)carve((size_t)N * 8);
    uint*  xb     = (uint*)carve((size_t)N * (D / 2) * 4);
    uint*  aggb   = (uint*)carve((size_t)N * (D / 2) * 4);
    uint*  hb     = (uint*)carve((size_t)N * (D / 2) * 4);
    uint*  wtbl   = (uint*)carve((size_t)L * 128 * 128 * 4);

    // ---- prep: conversions + edge binning (fused), then per-bucket CSR ----
    hipMemsetAsync(bcur, 0, 256 * 4, stream);
    const int n8 = N * D / 8;
    const int wtotal = L * 32768;
    const int nbConv = (n8 + 255) / 256;
    const int nbW = (wtotal + 255) / 256;
    const int nbSort = (E + CH1 - 1) / CH1;
    k_prep<<<nbConv + nbW + nbSort, 256, 0, stream>>>(
        x, xb, n8, W_neigh, W_self, (ushort*)wtbl, wtotal,
        src, dst, ew, E, bcur, bedge, nbConv, nbW);
    k_sort2<<<B, 512, 0, stream>>>(bedge, bcur, N, rsdeg, srcw);

    // ---- layers ----
    const int nblk_agg  = (N + 3) / 4;
    const int nblk_gemm = (N + 63) / 64;
    const uint* cur = xb;
    for (int l = 0; l < L; ++l) {
        const uint* wtl = wtbl + (size_t)l * 128 * 128;
        const float* bl = bias + (size_t)l * D;

        k_agg<<<nblk_agg, 256, 0, stream>>>(cur, srcw, rsdeg, aggb, N);
        if (l < L - 1) {
            k_gemm_mfma<0, 1><<<nblk_gemm, 256, 0, stream>>>(aggb, cur, wtl, bl, hb, N);
            cur = hb;
        } else {
            k_gemm_mfma<1, 0><<<nblk_gemm, 256, 0, stream>>>(aggb, cur, wtl, bl, out, N);
        }
    }
}